// Round 3
// baseline (126.534 us; speedup 1.0000x reference)
//
#include <hip/hip_runtime.h>

#define S_ROWS 2048
#define RO_ROWS 8192
#define HEADS 8
#define HDIM 32
#define ROWLEN 256   // HEADS * HDIM

typedef __attribute__((ext_vector_type(8))) short bf16x8;
typedef __attribute__((ext_vector_type(4))) float f32x4;
typedef __attribute__((ext_vector_type(4))) short s16x4;

__device__ __forceinline__ short f32_to_bf16_rne(float f) {
    union { float f; unsigned u; } v; v.f = f;
    return (short)((v.u + 0x7fffu + ((v.u >> 16) & 1u)) >> 16);
}

// Normalize every 32-element head vector of both inputs, emit bf16.
// float4 per thread: one head vector = 8 consecutive lanes; shfl_xor 1/2/4
// reduces the squared norm within the 8-lane group.
__global__ __launch_bounds__(256) void mhd_normalize(const float* __restrict__ s,
                                                     const float* __restrict__ ro,
                                                     short* __restrict__ outN) {
    const int idx = blockIdx.x * 256 + threadIdx.x;       // vec4 index
    const int S_TOT4 = S_ROWS * ROWLEN / 4;
    f32x4 x = (idx < S_TOT4) ? ((const f32x4*)s)[idx]
                             : ((const f32x4*)ro)[idx - S_TOT4];
    float ss = x[0] * x[0] + x[1] * x[1] + x[2] * x[2] + x[3] * x[3];
    ss += __shfl_xor(ss, 1);
    ss += __shfl_xor(ss, 2);
    ss += __shfl_xor(ss, 4);
    const float inv = rsqrtf(ss);
    s16x4 r;
    r[0] = f32_to_bf16_rne(x[0] * inv);
    r[1] = f32_to_bf16_rne(x[1] * inv);
    r[2] = f32_to_bf16_rne(x[2] * inv);
    r[3] = f32_to_bf16_rne(x[3] * inv);
    ((s16x4*)outN)[idx] = r;
}

// Wave tile 32x64 (s-rows x ro-cols): per head 2 A-frags + 4 B-frags,
// 8 MFMAs (16x16x32, K=32==HDIM, C=0), elementwise max into running max.
// Block = 4 waves stacked on rows -> block tile 128x64; grid = 16x128 = 2048
// blocks = 8192 waves = 32 waves/CU (needs VGPR<=64 for 8 waves/SIMD).
// mfma(b, a): D col=lane&15 = s-row, reg axis = 4 consecutive ro-cols
// -> float4 non-temporal stores (keep L2 clean for the bf16 inputs).
__global__ __launch_bounds__(256) void mhd_dist(const short* __restrict__ sN,
                                                const short* __restrict__ roN,
                                                float* __restrict__ out) {
    const int lane = threadIdx.x & 63;
    const int wave = threadIdx.x >> 6;   // 4 waves: rows 32*wave .. +31
    const int tile_r = blockIdx.x >> 7;  // 16 row tiles of 128
    const int tile_c = blockIdx.x & 127; // 128 col tiles of 64
    const int row0 = tile_r * 128 + wave * 32;
    const int col0 = tile_c * 64;
    const int l15 = lane & 15;
    const int kg = lane >> 4;

    f32x4 runmax[2][4];
#pragma unroll
    for (int i = 0; i < 2; ++i)
#pragma unroll
        for (int j = 0; j < 4; ++j)
            runmax[i][j] = (f32x4){-3.0e38f, -3.0e38f, -3.0e38f, -3.0e38f};

    const size_t aBase = (size_t)(row0 + l15) * ROWLEN + kg * 8;
    const size_t bBase = (size_t)(col0 + l15) * ROWLEN + kg * 8;

#pragma unroll 1
    for (int h = 0; h < HEADS; ++h) {
        const size_t hoff = (size_t)h * HDIM;
        bf16x8 a[2], b[4];
#pragma unroll
        for (int i = 0; i < 2; ++i)
            a[i] = *(const bf16x8*)(sN + aBase + (size_t)i * 16 * ROWLEN + hoff);
#pragma unroll
        for (int j = 0; j < 4; ++j)
            b[j] = *(const bf16x8*)(roN + bBase + (size_t)j * 16 * ROWLEN + hoff);
#pragma unroll
        for (int i = 0; i < 2; ++i)
#pragma unroll
            for (int j = 0; j < 4; ++j) {
                f32x4 acc = {0.f, 0.f, 0.f, 0.f};
                acc = __builtin_amdgcn_mfma_f32_16x16x32_bf16(b[j], a[i], acc, 0, 0, 0);
#pragma unroll
                for (int q = 0; q < 4; ++q)
                    runmax[i][j][q] = fmaxf(runmax[i][j][q], acc[q]);
            }
    }

    // lane holds: rows row0+i*16+l15, cols col0+j*16+kg*4 .. +3 -> float4 nt
#pragma unroll
    for (int i = 0; i < 2; ++i) {
        float* rowp = out + (size_t)(row0 + i * 16 + l15) * RO_ROWS + col0 + kg * 4;
#pragma unroll
        for (int j = 0; j < 4; ++j)
            __builtin_nontemporal_store(runmax[i][j], (f32x4*)(rowp + j * 16));
    }
}

extern "C" void kernel_launch(void* const* d_in, const int* in_sizes, int n_in,
                              void* d_out, int out_size, void* d_ws, size_t ws_size,
                              hipStream_t stream) {
    const float* batch_s  = (const float*)d_in[0];
    const float* batch_ro = (const float*)d_in[1];
    float* out = (float*)d_out;

    short* sN  = (short*)d_ws;                 // 2048*256 bf16 = 1 MiB
    short* roN = sN + (size_t)S_ROWS * ROWLEN; // 8192*256 bf16 = 4 MiB

    const int totalV4 = (S_ROWS + RO_ROWS) * ROWLEN / 4;   // 655360 (exact x256)
    mhd_normalize<<<totalV4 / 256, 256, 0, stream>>>(batch_s, batch_ro, sN);

    mhd_dist<<<(S_ROWS / 128) * (RO_ROWS / 64), 256, 0, stream>>>(sN, roN, out);
}

// Round 4
// 97.349 us; speedup vs baseline: 1.2998x; 1.2998x over previous
//
#include <hip/hip_runtime.h>

#define S_ROWS 2048
#define RO_ROWS 8192
#define HEADS 8
#define HDIM 32
#define ROWLEN 256           // HEADS * HDIM
#define NB_S (S_ROWS / 16)   // 128 fragment-blocks of s
#define NB_RO (RO_ROWS / 16) // 512 fragment-blocks of ro

typedef __attribute__((ext_vector_type(8))) short bf16x8;
typedef __attribute__((ext_vector_type(4))) float f32x4;
typedef __attribute__((ext_vector_type(4))) short s16x4;

__device__ __forceinline__ short f32_to_bf16_rne(float f) {
    union { float f; unsigned u; } v; v.f = f;
    return (short)((v.u + 0x7fffu + ((v.u >> 16) & 1u)) >> 16);
}

// Normalize every 32-elem head vector of both inputs; emit bf16 in
// FRAGMENT-MAJOR layout [H][N/16][16][32]: one 16-row x 32-col MFMA fragment
// is a contiguous 1 KiB block, so the dist kernel's loads are fully
// coalesced. One thread = 4 consecutive elems; 8 consecutive lanes = one
// head vector (shfl_xor 1/2/4 reduces the squared norm).
__global__ __launch_bounds__(256) void mhd_normalize(const float* __restrict__ s,
                                                     const float* __restrict__ ro,
                                                     short* __restrict__ sF,
                                                     short* __restrict__ roF) {
    const int idx = blockIdx.x * 256 + threadIdx.x;       // vec4 index
    const int S_TOT4 = S_ROWS * ROWLEN / 4;               // 131072 (x256 blocks)
    const bool isS = idx < S_TOT4;
    const int li = isS ? idx : idx - S_TOT4;
    f32x4 x = isS ? ((const f32x4*)s)[li] : ((const f32x4*)ro)[li];
    float ss = x[0] * x[0] + x[1] * x[1] + x[2] * x[2] + x[3] * x[3];
    ss += __shfl_xor(ss, 1);
    ss += __shfl_xor(ss, 2);
    ss += __shfl_xor(ss, 4);
    const float inv = rsqrtf(ss);
    s16x4 r;
    r[0] = f32_to_bf16_rne(x[0] * inv);
    r[1] = f32_to_bf16_rne(x[1] * inv);
    r[2] = f32_to_bf16_rne(x[2] * inv);
    r[3] = f32_to_bf16_rne(x[3] * inv);

    const int n   = li >> 6;          // source row
    const int rem = li & 63;
    const int h   = rem >> 3;         // head
    const int dg  = rem & 7;          // 4-elem group within head (d = dg*4)
    const int NB  = isS ? NB_S : NB_RO;
    short* base   = isS ? sF : roF;
    const size_t off = (((size_t)(h * NB + (n >> 4)) * 16 + (n & 15)) * 32) + dg * 4;
    *(s16x4*)(base + off) = r;
}

// Wave tile 64x64 (s-rows x ro-cols); block = 4 waves (2x2) -> 128x128 tile;
// grid 16x64 = 1024 blocks. Per head: 4 A-frags + 4 B-frags, each one
// contiguous 1 KiB load from the fragment-major workspace; 16 MFMAs
// (16x16x32, K=32==HDIM, C=0); elementwise max into running max.
// mfma(b, a): D lane-axis (lane&15) = s-row, reg-axis = ro-col.
// Epilogue repacks each 16x64 chunk through wave-private padded LDS so the
// global stores are 4 x 256B row segments per instruction (vs 16 x 64B raw).
__global__ __launch_bounds__(256, 4) void mhd_dist(const short* __restrict__ sF,
                                                   const short* __restrict__ roF,
                                                   float* __restrict__ out) {
    __shared__ float lds[4][16][68];  // 68 = 64 + 4 pad -> bank-floor r/w
    const int lane = threadIdx.x & 63;
    const int wave = threadIdx.x >> 6;
    const int wr = wave >> 1;
    const int wc = wave & 1;
    const int tile_r = blockIdx.x >> 6;   // 16 row tiles of 128
    const int tile_c = blockIdx.x & 63;   // 64 col tiles of 128
    const int l15 = lane & 15;
    const int kg = lane >> 4;

    f32x4 runmax[4][4];
#pragma unroll
    for (int i = 0; i < 4; ++i)
#pragma unroll
        for (int j = 0; j < 4; ++j)
            runmax[i][j] = (f32x4){-3.0e38f, -3.0e38f, -3.0e38f, -3.0e38f};

    const int nbA = tile_r * 8 + wr * 4;          // first s fragment-block
    const int nbB = tile_c * 8 + wc * 4;          // first ro fragment-block
    const size_t laneOff = (size_t)l15 * 32 + kg * 8;

#pragma unroll 1
    for (int h = 0; h < HEADS; ++h) {
        const short* aBase = sF  + (size_t)(h * NB_S  + nbA) * 512 + laneOff;
        const short* bBase = roF + (size_t)(h * NB_RO + nbB) * 512 + laneOff;
        bf16x8 a[4], b[4];
#pragma unroll
        for (int i = 0; i < 4; ++i) {
            a[i] = *(const bf16x8*)(aBase + (size_t)i * 512);
            b[i] = *(const bf16x8*)(bBase + (size_t)i * 512);
        }
#pragma unroll
        for (int i = 0; i < 4; ++i)
#pragma unroll
            for (int j = 0; j < 4; ++j) {
                f32x4 acc = {0.f, 0.f, 0.f, 0.f};
                acc = __builtin_amdgcn_mfma_f32_16x16x32_bf16(b[j], a[i], acc, 0, 0, 0);
#pragma unroll
                for (int q = 0; q < 4; ++q)
                    runmax[i][j][q] = fmaxf(runmax[i][j][q], acc[q]);
            }
    }

    // Epilogue: per 16-row chunk i, repack D-layout -> row-major via LDS,
    // then 4 store instructions of 4 rows x 256B each. Wave-private LDS
    // region => no barriers; compiler orders same-wave LDS ops via lgkmcnt.
    float* outBase = out + (size_t)(tile_r * 128 + wr * 64) * RO_ROWS
                         + tile_c * 128 + wc * 64;
    const int srow = lane >> 4;        // 0..3 rows per store instr
    const int scol = (lane & 15) * 4;  // f32 col within the 64-wide tile
#pragma unroll
    for (int i = 0; i < 4; ++i) {
#pragma unroll
        for (int j = 0; j < 4; ++j)
            *(f32x4*)&lds[wave][l15][kg * 4 + j * 16] = runmax[i][j];
#pragma unroll
        for (int t = 0; t < 4; ++t) {
            const int rowL = t * 4 + srow;
            f32x4 v = *(const f32x4*)&lds[wave][rowL][scol];
            *(f32x4*)(outBase + (size_t)(i * 16 + rowL) * RO_ROWS + scol) = v;
        }
    }
}

extern "C" void kernel_launch(void* const* d_in, const int* in_sizes, int n_in,
                              void* d_out, int out_size, void* d_ws, size_t ws_size,
                              hipStream_t stream) {
    const float* batch_s  = (const float*)d_in[0];
    const float* batch_ro = (const float*)d_in[1];
    float* out = (float*)d_out;

    short* sF  = (short*)d_ws;                  // 2048*256 bf16 = 1 MiB
    short* roF = sF + (size_t)S_ROWS * ROWLEN;  // 8192*256 bf16 = 4 MiB

    const int totalV4 = (S_ROWS + RO_ROWS) * ROWLEN / 4;   // 655360 (exact x256)
    mhd_normalize<<<totalV4 / 256, 256, 0, stream>>>(batch_s, batch_ro, sF, roF);

    mhd_dist<<<(S_ROWS / 128) * (RO_ROWS / 128), 256, 0, stream>>>(sF, roF, out);
}